// Round 5
// baseline (826.751 us; speedup 1.0000x reference)
//
#include <hip/hip_runtime.h>

// ============================================================================
// Djpegnet round 11.
//  - conv5_mfma A-tile stride HCP = W+5 (ODD): old stride (W+4)*16B == 16
//    banks mod 32 made row-pairs inside each wave64 b128 collide 4-way
//    (counter: 6.8M conflict cyc/dispatch = 22% tax on the LDS-read phase).
//    Odd stride == 20 mod 32 spreads 8 rows over all 8 bank slots. Free.
//  - Per-wave K-ROTATION: wave w starts the 13-step tap loop at p=(5w)%13,
//    so at any instant ~half the waves issue ds_reads while half issue MFMAs
//    -> de-phase-locks the LDS and MFMA pipes across waves (4 scheduling
//    attempts inside the wave were all null; this attacks the cross-wave
//    lockstep instead). Incremental per-lane tap decode (~11 VALU/step,
//    no divs, no dynamic arrays). fp32 accumulation order changes only.
//  - setprio kept (rotation creates the wave role diversity T5 needs).
//  - Everything else (flat-pair K=26, 512-thr/8-wave, staging, epilogue,
//    fc stack) = round 10 minus sched_group_barrier.
// ============================================================================

typedef _Float16 half8 __attribute__((ext_vector_type(8)));
typedef _Float16 half4 __attribute__((ext_vector_type(4)));
typedef float f32x16 __attribute__((ext_vector_type(16)));

__device__ __forceinline__ void async_copy16(const void* g, void* l) {
  __builtin_amdgcn_global_load_lds(
      (__attribute__((address_space(1))) void*)g,
      (__attribute__((address_space(3))) void*)l, 16, 0, 0);
}

// ---------------------------------------------------------------- DCT ------
__global__ __launch_bounds__(256) void dct_kernel(const float* __restrict__ x,
                                                  const float* __restrict__ basis,
                                                  float* __restrict__ dct) {
  __shared__ __align__(16) float Bm[64];
  int tid = threadIdx.x;
  if (tid < 64) {
    int u = tid >> 3, xx = tid & 7;
    Bm[tid] = basis[(u * 8) * 64 + xx * 8] * 2.8284271247461903f;
  }
  __syncthreads();
  int gid = blockIdx.x * 256 + tid;
  int b = gid >> 10, blk = gid & 1023;
  int bi = blk >> 5, bj = blk & 31;
  const float* xp = x + (size_t)b * 65536 + (bi * 8) * 256 + bj * 8;
  float X[64];
#pragma unroll
  for (int r = 0; r < 8; ++r) {
    float4 p = *(const float4*)(xp + r * 256);
    float4 q = *(const float4*)(xp + r * 256 + 4);
    X[r * 8 + 0] = p.x; X[r * 8 + 1] = p.y; X[r * 8 + 2] = p.z; X[r * 8 + 3] = p.w;
    X[r * 8 + 4] = q.x; X[r * 8 + 5] = q.y; X[r * 8 + 6] = q.z; X[r * 8 + 7] = q.w;
  }
  float T[64];
#pragma unroll
  for (int u = 0; u < 8; ++u) {
    float t[8] = {0.f, 0.f, 0.f, 0.f, 0.f, 0.f, 0.f, 0.f};
#pragma unroll
    for (int xx = 0; xx < 8; ++xx) {
      float bm = Bm[u * 8 + xx];
#pragma unroll
      for (int y = 0; y < 8; ++y) t[y] += bm * X[xx * 8 + y];
    }
#pragma unroll
    for (int y = 0; y < 8; ++y) T[u * 8 + y] = t[y];
  }
  float* op = dct + (size_t)b * 65536 + bi * 32 + bj;
#pragma unroll
  for (int v = 0; v < 8; ++v) {
    float dc[8] = {0.f, 0.f, 0.f, 0.f, 0.f, 0.f, 0.f, 0.f};
#pragma unroll
    for (int y = 0; y < 8; ++y) {
      float bm = Bm[v * 8 + y];
#pragma unroll
      for (int u = 0; u < 8; ++u) dc[u] += bm * T[u * 8 + y];
    }
#pragma unroll
    for (int u = 0; u < 8; ++u) op[(u * 8 + v) * 1024] = dc[u];
  }
}

// ---------------------------------------------------- soft histogram -------
__global__ __launch_bounds__(256) void hist_kernel(const float* __restrict__ dct,
                                                   float* __restrict__ feat) {
  __shared__ __align__(16) float h[16 * 121];
  int tid = threadIdx.x;
  for (int i = tid; i < 16 * 121; i += 256) h[i] = 0.f;
  __syncthreads();
  int b = blockIdx.x >> 6, c = blockIdx.x & 63;
  const float* dp = dct + (size_t)(b * 64 + c) * 1024;
  float* hc = h + (tid & 15) * 121;
  float4 v4 = ((const float4*)dp)[tid];
  float vals[4] = {v4.x, v4.y, v4.z, v4.w};
#pragma unroll
  for (int i = 0; i < 4; ++i) {
    float d = vals[i];
    float fl = floorf(d);
    float t0 = d - fl;
    int k = (int)fl + 60;
    if (t0 >= 2e-5f && t0 <= 1.f - 1.2e-4f) {
      if (k >= 0 && k < 120) atomicAdd(hc + k, 1.0f);
    } else {
      float s0 = 1.f / (1.f + expf(-1e6f * t0));
      float s1 = 1.f / (1.f + expf(1e6f * (1.f - t0)));
      if (k >= 1 && k <= 120) atomicAdd(hc + k - 1, 1.f - s0);
      if (k >= 0 && k < 120)  atomicAdd(hc + k, s0 - s1);
      if (k >= -1 && k < 119) atomicAdd(hc + k + 1, s1);
    }
  }
  __syncthreads();
  for (int f = tid; f < 120; f += 256) {
    float s = 0.f;
#pragma unroll
    for (int l = 0; l < 16; ++l) s += h[l * 121 + f];
    feat[((size_t)b * 120 + f) * 64 + c] = s * (1.f / 1024.f);
  }
}

// ---------------------------------------- weight transpose + BN folding ----
// wt layout: [cg][k26][co][8ci], cg = ci/8, k26 = kh*5+kw (k==25 zeroed).
template <int CI, int CO>
__global__ __launch_bounds__(256) void wtrans(const float* __restrict__ w,
                                              _Float16* __restrict__ wt) {
  int i = blockIdx.x * 256 + threadIdx.x;
  if (i >= (CI / 8) * 26 * CO * 8) return;
  int c8 = i & 7;
  int t = i >> 3;
  int co = t % CO; t /= CO;
  int k = t % 26;
  int cg = t / 26;
  int ci = cg * 8 + c8;
  float v = (k < 25) ? w[((size_t)co * CI + ci) * 25 + k] : 0.f;
  wt[i] = (_Float16)v;
}

__global__ __launch_bounds__(256) void bnprep(const float* __restrict__ cb,
                                              const float* __restrict__ s,
                                              const float* __restrict__ b,
                                              const float* __restrict__ m,
                                              const float* __restrict__ v,
                                              float* __restrict__ scale,
                                              float* __restrict__ shift, int n) {
  int i = threadIdx.x;
  if (i < n) {
    float inv = s[i] * rsqrtf(v[i] + 1e-5f);
    scale[i] = inv;
    shift[i] = (cb[i] - m[i]) * inv + b[i];
  }
}

// -------------------------- conv1a: fp32 direct, out grouped-NHWC f16 ------
__global__ __launch_bounds__(256) void conv1a_f16(
    const float* __restrict__ in, const float* __restrict__ wts,
    const float* __restrict__ cb, const float* __restrict__ s_,
    const float* __restrict__ b_, const float* __restrict__ m_,
    const float* __restrict__ v_, _Float16* __restrict__ out) {
  __shared__ __align__(16) float wl[5 * 8 * 20];
  __shared__ __align__(16) float il[12 * 68];
  int tid = threadIdx.x, bid = blockIdx.x;
  int img = bid / 30;
  int r = bid % 30;
  int cob = r / 15;
  int h0 = (r % 15) * 8;
  int cog = tid & 7, wg = (tid >> 3) & 3, hh = tid >> 5;
  float acc[4][16];
#pragma unroll
  for (int i = 0; i < 4; ++i)
#pragma unroll
    for (int j = 0; j < 16; ++j) acc[i][j] = 0.f;
  for (int idx = tid; idx < 32 * 25; idx += 256) {
    int rr = idx % 25, co = idx / 25;
    float v = wts[(cob * 32 + co) * 25 + rr];
    int kh = rr / 5, kw = rr % 5;
    wl[(kh * 8 + (co >> 2)) * 20 + (co & 3) * 5 + kw] = v;
  }
  for (int idx = tid; idx < 12 * 68; idx += 256) {
    int cc = idx % 68, rr = idx / 68;
    int hy = h0 + rr - 2, wx = cc - 2;
    float v = 0.f;
    if (hy >= 0 && hy < 120 && wx >= 0 && wx < 64)
      v = in[(size_t)img * 7680 + hy * 64 + wx];
    il[idx] = v;
  }
  __syncthreads();
#pragma unroll
  for (int kh = 0; kh < 5; ++kh) {
    const float* ir = &il[(hh + kh) * 68 + wg * 16];
    float iv[20];
#pragma unroll
    for (int i = 0; i < 5; ++i) {
      float4 p = *(const float4*)(ir + i * 4);
      iv[i * 4] = p.x; iv[i * 4 + 1] = p.y; iv[i * 4 + 2] = p.z; iv[i * 4 + 3] = p.w;
    }
    const float* wr = &wl[(kh * 8 + cog) * 20];
    float wv[20];
#pragma unroll
    for (int i = 0; i < 5; ++i) {
      float4 p = *(const float4*)(wr + i * 4);
      wv[i * 4] = p.x; wv[i * 4 + 1] = p.y; wv[i * 4 + 2] = p.z; wv[i * 4 + 3] = p.w;
    }
#pragma unroll
    for (int co = 0; co < 4; ++co)
#pragma unroll
      for (int kw = 0; kw < 5; ++kw) {
        float w1 = wv[co * 5 + kw];
#pragma unroll
        for (int w = 0; w < 16; ++w) acc[co][w] += w1 * iv[w + kw];
      }
  }
  int h = h0 + hh;
  int co0 = cob * 32 + cog * 4;
  float inv[4], bia[4];
#pragma unroll
  for (int i = 0; i < 4; ++i) {
    int c = co0 + i;
    inv[i] = s_[c] * rsqrtf(v_[c] + 1e-5f);
    bia[i] = (cb[c] - m_[c]) * inv[i] + b_[c];
  }
  int g = co0 >> 3, off = co0 & 7;
  _Float16* op = out + (((size_t)(img * 8 + g) * 120 + h) * 64) * 8 + off;
#pragma unroll
  for (int w = 0; w < 16; ++w) {
    half4 o;
#pragma unroll
    for (int i = 0; i < 4; ++i)
      o[i] = (_Float16)fmaxf(acc[i][w] * inv[i] + bia[i], 0.f);
    *(half4*)&op[(size_t)(wg * 16 + w) * 8] = o;
  }
}

// ------------------ MFMA implicit-GEMM 5x5 conv + BN + ReLU + maxpool2 -----
// 512 threads / 8 waves. Flat-pair K: 13 K=16 steps cover 25 taps + 1 pad.
// A-tile stride HCP = W+5 (odd -> bank-spread). Per-wave rotated K start.
// Output POOLED: grouped [img][CO/8][H/2][W/2][8] or (OUT_NCHW)
// [img][CO][H/2][W/2]. Requires W in {64,32,16}, ROWS even.
template <int CI, int CO, int H, int W, int BLK_M, bool OUT_NCHW, bool DBUF>
__global__ __launch_bounds__(512) void conv5_mfma(
    const _Float16* __restrict__ in, const _Float16* __restrict__ wt,
    const float* __restrict__ scale, const float* __restrict__ shift,
    _Float16* __restrict__ out) {
  constexpr int NW_M = BLK_M / 64;
  constexpr int NW_N = 8 / NW_M;
  constexpr int BLK_N = NW_N * 128;
  constexpr int ROWS = BLK_N / W;
  constexpr int TB = (H + ROWS - 1) / ROWS;
  constexpr int NCOB = CO / BLK_M;
  constexpr int HR = ROWS + 4;
  constexpr int HCP = W + 5;  // odd stride: == 20 mod 32 banks, spreads rows
  constexpr int CIG = CI / 8;
  constexpr int OH = H / 2, OW = W / 2;
  constexpr int AITER = (HR * HCP + 511) / 512;
  constexpr int WBYTES = 26 * BLK_M * 16;
  constexpr int WITER = (WBYTES + 8191) / 8192;
  constexpr int NBUF = DBUF ? 2 : 1;
  constexpr int ASZ = HR * HCP * 8;
  constexpr int WSZ = 26 * BLK_M * 8;
  __shared__ __align__(16) _Float16 Alds[NBUF][ASZ];
  __shared__ __align__(16) _Float16 Wlds[NBUF][WSZ];

  int tid = threadIdx.x;
  int bid = blockIdx.x;
  int img = bid / (TB * NCOB);
  int r = bid % (TB * NCOB);
  int tb = r / NCOB;
  int cob = r % NCOB;
  int h0 = tb * ROWS;

  int wid = tid >> 6, l = tid & 63, lo = l & 31, hi = l >> 5;
  int widM = wid / NW_N, widN = wid % NW_N;

  int wbase[2];
#pragma unroll
  for (int mi = 0; mi < 2; ++mi)
    wbase[mi] = (hi * BLK_M + widM * 64 + mi * 32 + lo) * 8;
  int blin[4];  // A-tile unit index of this lane's pixel (row*HCP + col)
#pragma unroll
  for (int j = 0; j < 4; ++j) {
    int pix = widN * 128 + j * 32 + lo;
    blin[j] = (pix / W) * HCP + (pix % W);
  }

  f32x16 acc[2][4];
#pragma unroll
  for (int mi = 0; mi < 2; ++mi)
#pragma unroll
    for (int j = 0; j < 4; ++j) acc[mi][j] = (f32x16){};

  auto loadA = [&](int cg, half8* areg) {
    const _Float16* ing = in + (size_t)(img * CIG + cg) * H * W * 8;
#pragma unroll
    for (int it = 0; it < AITER; ++it) {
      int i = tid + it * 512;
      half8 v = {};
      if (i < HR * HCP) {
        int rr = i / HCP, cc = i % HCP;
        int hy = h0 + rr - 2, wx = cc - 2;
        if (hy >= 0 && hy < H && wx >= 0 && wx < W)
          v = *(const half8*)&ing[(size_t)(hy * W + wx) * 8];
      }
      areg[it] = v;
    }
  };
  auto issueW = [&](int cg, int buf) {
    const char* wsrc = (const char*)(wt + ((size_t)cg * 26 * CO + cob * BLK_M) * 8);
#pragma unroll
    for (int rr = 0; rr < WITER; ++rr) {
      int f = rr * 8192 + tid * 16;
      if (f < WBYTES) {
        int row = f / (BLK_M * 16);
        int off = f % (BLK_M * 16);
        async_copy16(wsrc + (size_t)row * (CO * 16) + off,
                     (char*)&Wlds[buf][0] + (rr * 8192 + wid * 1024));
      }
    }
  };
  auto writeA = [&](int buf, half8* areg) {
#pragma unroll
    for (int it = 0; it < AITER; ++it) {
      int i = tid + it * 512;
      if (i < HR * HCP) *(half8*)&Alds[buf][i * 8] = areg[it];
    }
  };
  // rotated, incrementally-decoded K loop: wave w starts at p=(5w)%13; each
  // lane tracks its own tap (pos = 2p + hi) as (kw, loff=kh*HCP+kw).
  auto compute = [&](int buf) {
    int p0 = (wid * 5) % 13;
    int mypos = 2 * p0 + hi;
    int kwv = mypos % 5;
    int loff = (mypos / 5) * HCP + kwv;
    if (mypos >= 25) { kwv = 0; loff = 0; }  // pad tap: value irrelevant (W row 25 = 0)
    int afoff = (2 * p0) * BLK_M * 8;
    int pcur = p0;
#pragma unroll 1
    for (int ps = 0; ps < 13; ++ps) {
      half8 af[2], bf[4];
#pragma unroll
      for (int mi = 0; mi < 2; ++mi)
        af[mi] = *(const half8*)&Wlds[buf][wbase[mi] + afoff];
#pragma unroll
      for (int j = 0; j < 4; ++j)
        bf[j] = *(const half8*)&Alds[buf][(blin[j] + loff) * 8];
      __builtin_amdgcn_s_setprio(1);
#pragma unroll
      for (int mi = 0; mi < 2; ++mi)
#pragma unroll
        for (int j = 0; j < 4; ++j)
          acc[mi][j] = __builtin_amdgcn_mfma_f32_32x32x16_f16(
              af[mi], bf[j], acc[mi][j], 0, 0, 0);
      __builtin_amdgcn_s_setprio(0);
      // advance this lane's tap by 2 (raster over 5x5), wrap p 13->0
      ++pcur;
      kwv += 2;
      bool w5 = kwv >= 5;
      kwv = w5 ? kwv - 5 : kwv;
      loff += w5 ? (HCP - 3) : 2;
      if (loff >= 5 * HCP) loff = 0;  // pos==25 pad tap -> safe in-bounds addr
      afoff += 2 * BLK_M * 8;
      if (pcur == 13) { pcur = 0; kwv = hi; loff = hi; afoff = 0; }
    }
  };

  if constexpr (DBUF) {
    half8 areg[AITER];
    loadA(0, areg);
    issueW(0, 0);
    writeA(0, areg);
    __syncthreads();
#pragma unroll 1
    for (int cg = 0; cg < CIG; ++cg) {
      int cur = cg & 1;
      if (cg + 1 < CIG) {
        loadA(cg + 1, areg);
        issueW(cg + 1, cur ^ 1);
      }
      compute(cur);
      if (cg + 1 < CIG) writeA(cur ^ 1, areg);
      __syncthreads();
    }
  } else {
#pragma unroll 1
    for (int cg = 0; cg < CIG; ++cg) {
      half8 areg[AITER];
      loadA(cg, areg);
      issueW(cg, 0);
      writeA(0, areg);
      __syncthreads();
      compute(0);
      __syncthreads();
    }
  }

  // ---- fused BN + ReLU + 2x2 maxpool epilogue ----
  if (!OUT_NCHW) {
    // W==64: rows widN*2+{0,1} = j pairs (0,2),(1,3); cols p*32+lo.
    // W==32: rows widN*4+j   = j pairs (0,1),(2,3); cols lo.
    constexpr int CGO = CO / 8;
    int gbase = (cob * BLK_M + widM * 64) >> 3;
    bool lane_ok = ((lo & 1) == 0);
#pragma unroll
    for (int mi = 0; mi < 2; ++mi) {
#pragma unroll
      for (int r4 = 0; r4 < 4; ++r4) {
        int g = gbase + mi * 4 + r4;
        int co0 = g * 8 + hi * 4;
        float4 sv = *(const float4*)&scale[co0];
        float4 tv = *(const float4*)&shift[co0];
        float sa[4] = {sv.x, sv.y, sv.z, sv.w};
        float ta[4] = {tv.x, tv.y, tv.z, tv.w};
#pragma unroll
        for (int p = 0; p < 2; ++p) {
          int ja = (W == 64) ? p : 2 * p;
          int jb = (W == 64) ? p + 2 : 2 * p + 1;
          int orow = (W == 64) ? (h0 >> 1) + widN : (h0 >> 1) + widN * 2 + p;
          int ocol = (W == 64) ? p * 16 + (lo >> 1) : (lo >> 1);
          half4 o;
#pragma unroll
          for (int c = 0; c < 4; ++c) {
            int reg = r4 * 4 + c;
            float v0 = fmaxf(acc[mi][ja][reg] * sa[c] + ta[c], 0.f);
            float v1 = fmaxf(acc[mi][jb][reg] * sa[c] + ta[c], 0.f);
            float m = fmaxf(v0, v1);
            m = fmaxf(m, __shfl_xor(m, 1, 64));
            o[c] = (_Float16)m;
          }
          if (lane_ok && orow < OH)
            *(half4*)&out[(((size_t)(img * CGO + g) * OH + orow) * OW + ocol) * 8 +
                          hi * 4] = o;
        }
      }
    }
  } else {
    // W==16: rows widN*8 + 2j + (lo>>4); row pair = lane^16, col pair = lane^1.
    bool lane_ok = ((lo & 1) == 0) && (lo < 16);
#pragma unroll
    for (int mi = 0; mi < 2; ++mi) {
#pragma unroll
      for (int reg = 0; reg < 16; ++reg) {
        int co = cob * BLK_M + widM * 64 + mi * 32 + (reg & 3) + 8 * (reg >> 2) + 4 * hi;
        float s = scale[co], t = shift[co];
#pragma unroll
        for (int j = 0; j < 4; ++j) {
          float v = fmaxf(acc[mi][j][reg] * s + t, 0.f);
          float m = fmaxf(v, __shfl_xor(v, 16, 64));
          m = fmaxf(m, __shfl_xor(m, 1, 64));
          int orow = (h0 >> 1) + widN * 4 + j;
          if (lane_ok && orow < OH)
            out[((size_t)(img * CO + co) * OH + orow) * OW + ((lo & 15) >> 1)] =
                (_Float16)m;
        }
      }
    }
  }
}

// --------------------------------------------------- fc1: f16 MFMA split-K -
// 240 K-splits x 2 N-tiles = 480 blocks. part[ks][n512][img128].
__global__ __launch_bounds__(256, 2) void fc1_mfma(const float* __restrict__ qv,
                                                   const _Float16* __restrict__ p3,
                                                   const float* __restrict__ w,
                                                   float* __restrict__ part) {
  __shared__ __align__(16) _Float16 Wl[8 * 256 * 8];  // [k8][n_loc][8]
  __shared__ __align__(16) _Float16 Bl[8 * 128 * 8];  // [k8][img][8]
  int tid = threadIdx.x;
  int ks = blockIdx.x >> 1, mt = blockIdx.x & 1;
  int wid = tid >> 6, l = tid & 63, lo = l & 31, hi = l >> 5;
  f32x16 acc[2][4];
#pragma unroll
  for (int mi = 0; mi < 2; ++mi)
#pragma unroll
    for (int j = 0; j < 4; ++j) acc[mi][j] = (f32x16){};

#pragma unroll 1
  for (int i3 = 0; i3 < 3; ++i3) {
    int c = ks + 240 * i3;
    if (c > 480) break;
    for (int idx = tid; idx < 2048; idx += 256) {
      int n_loc = idx >> 3, k8 = idx & 7;
      int n = mt * 256 + n_loc;
      half8 v = {};
      if (n < 500) {
        const float* src = w + (size_t)n * 30784 + c * 64 + k8 * 8;
        float4 f0 = *(const float4*)src;
        float4 f1 = *(const float4*)(src + 4);
        v[0] = (_Float16)f0.x; v[1] = (_Float16)f0.y;
        v[2] = (_Float16)f0.z; v[3] = (_Float16)f0.w;
        v[4] = (_Float16)f1.x; v[5] = (_Float16)f1.y;
        v[6] = (_Float16)f1.z; v[7] = (_Float16)f1.w;
      }
      *(half8*)&Wl[(size_t)(k8 * 256 + n_loc) * 8] = v;
    }
    for (int idx = tid; idx < 1024; idx += 256) {
      int img = idx >> 3, k8 = idx & 7;
      half8 v;
      if (c == 0) {
        const float* src = qv + img * 64 + k8 * 8;
        float4 f0 = *(const float4*)src;
        float4 f1 = *(const float4*)(src + 4);
        v[0] = (_Float16)f0.x; v[1] = (_Float16)f0.y;
        v[2] = (_Float16)f0.z; v[3] = (_Float16)f0.w;
        v[4] = (_Float16)f1.x; v[5] = (_Float16)f1.y;
        v[6] = (_Float16)f1.z; v[7] = (_Float16)f1.w;
      } else {
        v = *(const half8*)&p3[(size_t)img * 30720 + (c * 64 - 64) + k8 * 8];
      }
      *(half8*)&Bl[(size_t)(k8 * 128 + img) * 8] = v;
    }
    __syncthreads();
#pragma unroll
    for (int ks16 = 0; ks16 < 4; ++ks16) {
      half8 af[2], bf[4];
#pragma unroll
      for (int mi = 0; mi < 2; ++mi)
        af[mi] = *(const half8*)&Wl[(size_t)((ks16 * 2 + hi) * 256 + wid * 64 +
                                             mi * 32 + lo) * 8];
#pragma unroll
      for (int j = 0; j < 4; ++j)
        bf[j] = *(const half8*)&Bl[(size_t)((ks16 * 2 + hi) * 128 + j * 32 + lo) * 8];
#pragma unroll
      for (int mi = 0; mi < 2; ++mi)
#pragma unroll
        for (int j = 0; j < 4; ++j)
          acc[mi][j] = __builtin_amdgcn_mfma_f32_32x32x16_f16(
              af[mi], bf[j], acc[mi][j], 0, 0, 0);
    }
    __syncthreads();
  }
#pragma unroll
  for (int mi = 0; mi < 2; ++mi)
#pragma unroll
    for (int reg = 0; reg < 16; ++reg) {
      int n = mt * 256 + wid * 64 + mi * 32 + (reg & 3) + 8 * (reg >> 2) + 4 * hi;
#pragma unroll
      for (int j = 0; j < 4; ++j)
        part[((size_t)ks * 512 + n) * 128 + j * 32 + lo] = acc[mi][j][reg];
    }
}

__global__ __launch_bounds__(256) void fc1_reduce(const float* __restrict__ part,
                                                  const float* __restrict__ bias,
                                                  float* __restrict__ out) {
  int idx = blockIdx.x * 256 + threadIdx.x;  // 65536 = 512 n x 128 img
  int img = idx & 127, n = idx >> 7;
  float s = 0.f;
#pragma unroll 8
  for (int ks = 0; ks < 240; ++ks) s += part[((size_t)ks * 512 + n) * 128 + img];
  out[n * 128 + img] = (n < 500) ? fmaxf(s + bias[n], 0.f) : 0.f;
}

// -------------------------------------------------------- fc2 / fc3 --------
__global__ __launch_bounds__(256) void fc2_kernel(const float* __restrict__ qv,
                                                  const float* __restrict__ fc1o,
                                                  const float* __restrict__ w,
                                                  const float* __restrict__ bias,
                                                  float* __restrict__ out) {
  int idx = blockIdx.x * 256 + threadIdx.x;
  if (idx >= 128 * 500) return;
  int m = idx & 127, n = idx >> 7;
  const float* wr = w + (size_t)n * 564;
  float acc = 0.f;
#pragma unroll 8
  for (int k = 0; k < 64; ++k) acc += qv[m * 64 + k] * wr[k];
#pragma unroll 4
  for (int k = 0; k < 500; ++k) acc += fc1o[k * 128 + m] * wr[64 + k];
  out[n * 128 + m] = fmaxf(acc + bias[n], 0.f);
}

__global__ __launch_bounds__(256) void fc3_kernel(const float* __restrict__ qv,
                                                  const float* __restrict__ fc2o,
                                                  const float* __restrict__ w,
                                                  const float* __restrict__ bias,
                                                  float* __restrict__ out) {
  int tid = threadIdx.x;
  int m = tid >> 1, n = tid & 1;
  const float* wr = w + (size_t)n * 564;
  float acc = 0.f;
#pragma unroll 8
  for (int k = 0; k < 64; ++k) acc += qv[m * 64 + k] * wr[k];
#pragma unroll 4
  for (int k = 0; k < 500; ++k) acc += fc2o[k * 128 + m] * wr[64 + k];
  out[m * 2 + n] = acc + bias[n];
}

// ----------------------------------------------------------- launcher ------
extern "C" void kernel_launch(void* const* d_in, const int* in_sizes, int n_in,
                              void* d_out, int out_size, void* d_ws, size_t ws_size,
                              hipStream_t stream) {
  (void)in_sizes; (void)n_in; (void)out_size; (void)ws_size;
  const float* x      = (const float*)d_in[0];
  const float* qv     = (const float*)d_in[1];
  const float* basis  = (const float*)d_in[2];
  const float* c1aw   = (const float*)d_in[3];
  const float* c1ab   = (const float*)d_in[4];
  const float* c1bw   = (const float*)d_in[5];
  const float* c1bb   = (const float*)d_in[6];
  const float* c2aw   = (const float*)d_in[7];
  const float* c2ab   = (const float*)d_in[8];
  const float* c3aw   = (const float*)d_in[9];
  const float* c3ab   = (const float*)d_in[10];
  const float* bn1a_s = (const float*)d_in[11];
  const float* bn1a_b = (const float*)d_in[12];
  const float* bn1a_m = (const float*)d_in[13];
  const float* bn1a_v = (const float*)d_in[14];
  const float* bn1b_s = (const float*)d_in[15];
  const float* bn1b_b = (const float*)d_in[16];
  const float* bn1b_m = (const float*)d_in[17];
  const float* bn1b_v = (const float*)d_in[18];
  const float* bn2a_s = (const float*)d_in[19];
  const float* bn2a_b = (const float*)d_in[20];
  const float* bn2a_m = (const float*)d_in[21];
  const float* bn2a_v = (const float*)d_in[22];
  const float* bn3a_s = (const float*)d_in[23];
  const float* bn3a_b = (const float*)d_in[24];
  const float* bn3a_m = (const float*)d_in[25];
  const float* bn3a_v = (const float*)d_in[26];
  const float* fc1w   = (const float*)d_in[27];
  const float* fc1b   = (const float*)d_in[28];
  const float* fc2w   = (const float*)d_in[29];
  const float* fc2b   = (const float*)d_in[30];
  const float* fc3w   = (const float*)d_in[31];
  const float* fc3b   = (const float*)d_in[32];

  // ---- workspace (fl units), peak ~29.6M fl = 118 MB ----
  float* ws = (float*)d_ws;
  float* feat = ws;                                   //   983,040
  _Float16* wt1b = (_Float16*)(ws + 1000000);         //   106,496 h
  _Float16* wt2a = (_Float16*)(ws + 1070000);         //   212,992 h
  _Float16* wt3a = (_Float16*)(ws + 1200000);         //   851,968 h
  float* sc1b = ws + 1700000; float* sh1b = ws + 1700100;
  float* sc2a = ws + 1700200; float* sh2a = ws + 1700400;
  float* sc3a = ws + 1700600; float* sh3a = ws + 1701000;
  _Float16* p1 = (_Float16*)(ws + 1710000);           // 15,728,640 h (full)
  float* S = ws + 9600000;
  float* dct     = S;                                 //  8,388,608 (dead early)
  _Float16* a1c  = (_Float16*)S;                      // 31,457,280 h (64-img chunk)
  _Float16* p2   = (_Float16*)(ws + 25400000);        //  7,864,320 h (full)
  _Float16* p3   = (_Float16*)(ws + 1710000);         //  3,932,160 h (p1 slot)
  float* f1p  = S;                                    // 15,728,640 fl (a1c dead)
  float* f1o  = ws + 29400000;                        //     65,536
  float* f2o  = ws + 29500000;                        //     65,536

  wtrans<64, 64><<<416, 256, 0, stream>>>(c1bw, wt1b);
  wtrans<64, 128><<<832, 256, 0, stream>>>(c2aw, wt2a);
  wtrans<128, 256><<<3328, 256, 0, stream>>>(c3aw, wt3a);
  bnprep<<<1, 256, 0, stream>>>(c1bb, bn1b_s, bn1b_b, bn1b_m, bn1b_v, sc1b, sh1b, 64);
  bnprep<<<1, 256, 0, stream>>>(c2ab, bn2a_s, bn2a_b, bn2a_m, bn2a_v, sc2a, sh2a, 128);
  bnprep<<<1, 256, 0, stream>>>(c3ab, bn3a_s, bn3a_b, bn3a_m, bn3a_v, sc3a, sh3a, 256);

  dct_kernel<<<512, 256, 0, stream>>>(x, basis, dct);
  hist_kernel<<<128 * 64, 256, 0, stream>>>(dct, feat);

  // ---- conv1a + conv1b(MFMA, pooled out) : 2 chunks of 64 images ----
  for (int c = 0; c < 2; ++c) {
    const float* fin = feat + (size_t)c * 64 * 120 * 64;
    _Float16* pout = p1 + (size_t)c * 64 * 8 * 60 * 32 * 8;
    conv1a_f16<<<64 * 30, 256, 0, stream>>>(fin, c1aw, c1ab, bn1a_s, bn1a_b,
                                            bn1a_m, bn1a_v, a1c);
    conv5_mfma<64, 64, 120, 64, 64, false, false><<<64 * 8, 512, 0, stream>>>(
        a1c, wt1b, sc1b, sh1b, pout);
  }

  // ---- conv2a (full batch, pooled out) ----
  conv5_mfma<64, 128, 60, 32, 128, false, false><<<128 * 4, 512, 0, stream>>>(
      p1, wt2a, sc2a, sh2a, p2);

  // ---- conv3a (full batch, pooled NCHW out) ----
  conv5_mfma<128, 256, 30, 16, 128, true, false><<<128 * 2, 512, 0, stream>>>(
      p2, wt3a, sc3a, sh3a, p3);

  // ---- FC stack ----
  fc1_mfma<<<480, 256, 0, stream>>>(qv, p3, fc1w, f1p);
  fc1_reduce<<<256, 256, 0, stream>>>(f1p, fc1b, f1o);
  fc2_kernel<<<250, 256, 0, stream>>>(qv, f1o, fc2w, fc2b, f2o);
  fc3_kernel<<<1, 256, 0, stream>>>(qv, f2o, fc3w, fc3b, (float*)d_out);
}

// Round 6
// 768.600 us; speedup vs baseline: 1.0757x; 1.0757x over previous
//
#include <hip/hip_runtime.h>

// ============================================================================
// Djpegnet round 12.
//  - conv5_mfma: exact round-8 configuration restored (best measured:
//    conv3a 97.2us, total 779.2). Rounds 9-11 proved the structure's
//    scheduling ceiling: SQ_LDS_BANK_CONFLICT is bit-identical across
//    stride/grid changes (= intrinsic b128 multi-cycle, not conflicts);
//    SW-pipe/DBUF/2-block/SGB/rotation all null or negative.
//  - DCT+HIST FUSED: dct coefficients histogrammed in-register -> LDS
//    (64ch x 120bins x 2 sub-hists = 61.4KB), killing the 134MB dct
//    buffer write + 134MB re-read (~45us HBM floor). Per-thread v-rotation
//    spreads concurrent atomics across 8 channels; partials (512 x 7680)
//    reduced by a tiny second kernel into feat.
//  - fc1 split-K 240 -> 120 splits (4-5 chunks each): part buffer traffic
//    halves (63 -> 31.5MB each way).
// ============================================================================

typedef _Float16 half8 __attribute__((ext_vector_type(8)));
typedef _Float16 half4 __attribute__((ext_vector_type(4)));
typedef float f32x16 __attribute__((ext_vector_type(16)));

__device__ __forceinline__ void async_copy16(const void* g, void* l) {
  __builtin_amdgcn_global_load_lds(
      (__attribute__((address_space(1))) void*)g,
      (__attribute__((address_space(3))) void*)l, 16, 0, 0);
}

// ------------------------------------------------- fused DCT + histogram ---
// 512 blocks (4 per image, 256 dct-blocks each), 256 threads.
// Each thread: one 8x8 block -> 64 coeffs in regs -> LDS channel histograms.
// hpart[gb][f(120)][c(64)] partial sums; reduced by hist_reduce.
__global__ __launch_bounds__(256) void dcthist_kernel(const float* __restrict__ x,
                                                      const float* __restrict__ basis,
                                                      float* __restrict__ hpart) {
  __shared__ __align__(16) float Bm[64];
  __shared__ float Hl[2 * 64 * 120];  // [sub][c][120]
  int tid = threadIdx.x;
  if (tid < 64) {
    int u = tid >> 3, xx = tid & 7;
    Bm[tid] = basis[(u * 8) * 64 + xx * 8] * 2.8284271247461903f;
  }
  for (int i = tid; i < 2 * 64 * 120; i += 256) Hl[i] = 0.f;
  __syncthreads();
  int gb = blockIdx.x;
  int b = gb >> 2;
  int blk = (gb & 3) * 256 + tid;
  int bi = blk >> 5, bj = blk & 31;
  const float* xp = x + (size_t)b * 65536 + (bi * 8) * 256 + bj * 8;
  float X[64];
#pragma unroll
  for (int r = 0; r < 8; ++r) {
    float4 p = *(const float4*)(xp + r * 256);
    float4 q = *(const float4*)(xp + r * 256 + 4);
    X[r * 8 + 0] = p.x; X[r * 8 + 1] = p.y; X[r * 8 + 2] = p.z; X[r * 8 + 3] = p.w;
    X[r * 8 + 4] = q.x; X[r * 8 + 5] = q.y; X[r * 8 + 6] = q.z; X[r * 8 + 7] = q.w;
  }
  float T[64];
#pragma unroll
  for (int u = 0; u < 8; ++u) {
    float t[8] = {0.f, 0.f, 0.f, 0.f, 0.f, 0.f, 0.f, 0.f};
#pragma unroll
    for (int xx = 0; xx < 8; ++xx) {
      float bm = Bm[u * 8 + xx];
#pragma unroll
      for (int y = 0; y < 8; ++y) t[y] += bm * X[xx * 8 + y];
    }
#pragma unroll
    for (int y = 0; y < 8; ++y) T[u * 8 + y] = t[y];
  }
  // histogram: v rotated per-thread (spreads atomics over 8 channels);
  // only LDS addresses are dynamic -- register arrays stay static-indexed.
  int vr = tid & 7;
  float* Hs = Hl + ((tid >> 3) & 1) * (64 * 120);
#pragma unroll 1
  for (int vv = 0; vv < 8; ++vv) {
    int v = (vv + vr) & 7;
    float dc[8] = {0.f, 0.f, 0.f, 0.f, 0.f, 0.f, 0.f, 0.f};
#pragma unroll
    for (int y = 0; y < 8; ++y) {
      float bm = Bm[v * 8 + y];
#pragma unroll
      for (int u = 0; u < 8; ++u) dc[u] += bm * T[u * 8 + y];
    }
#pragma unroll
    for (int u = 0; u < 8; ++u) {
      float d = dc[u];
      float* hc = Hs + (u * 8 + v) * 120;
      float fl = floorf(d);
      float t0 = d - fl;
      int k = (int)fl + 60;
      if (t0 >= 2e-5f && t0 <= 1.f - 1.2e-4f) {
        if (k >= 0 && k < 120) atomicAdd(hc + k, 1.0f);
      } else {
        float s0 = 1.f / (1.f + expf(-1e6f * t0));
        float s1 = 1.f / (1.f + expf(1e6f * (1.f - t0)));
        if (k >= 1 && k <= 120) atomicAdd(hc + k - 1, 1.f - s0);
        if (k >= 0 && k < 120)  atomicAdd(hc + k, s0 - s1);
        if (k >= -1 && k < 119) atomicAdd(hc + k + 1, s1);
      }
    }
  }
  __syncthreads();
  for (int i = tid; i < 7680; i += 256) {
    int f = i >> 6, c = i & 63;
    hpart[(size_t)gb * 7680 + i] = Hl[c * 120 + f] + Hl[64 * 120 + c * 120 + f];
  }
}

__global__ __launch_bounds__(256) void hist_reduce(const float* __restrict__ hpart,
                                                   float* __restrict__ feat) {
  int idx = blockIdx.x * 256 + threadIdx.x;  // 983040 = 128 img x 7680
  int b = idx / 7680, r = idx - b * 7680;
  float s = 0.f;
#pragma unroll
  for (int q = 0; q < 4; ++q) s += hpart[(size_t)(b * 4 + q) * 7680 + r];
  feat[(size_t)b * 7680 + r] = s * (1.f / 1024.f);
}

// ---------------------------------------- weight transpose + BN folding ----
// wt layout: [cg][k26][co][8ci], cg = ci/8, k26 = kh*5+kw (k==25 zeroed).
template <int CI, int CO>
__global__ __launch_bounds__(256) void wtrans(const float* __restrict__ w,
                                              _Float16* __restrict__ wt) {
  int i = blockIdx.x * 256 + threadIdx.x;
  if (i >= (CI / 8) * 26 * CO * 8) return;
  int c8 = i & 7;
  int t = i >> 3;
  int co = t % CO; t /= CO;
  int k = t % 26;
  int cg = t / 26;
  int ci = cg * 8 + c8;
  float v = (k < 25) ? w[((size_t)co * CI + ci) * 25 + k] : 0.f;
  wt[i] = (_Float16)v;
}

__global__ __launch_bounds__(256) void bnprep(const float* __restrict__ cb,
                                              const float* __restrict__ s,
                                              const float* __restrict__ b,
                                              const float* __restrict__ m,
                                              const float* __restrict__ v,
                                              float* __restrict__ scale,
                                              float* __restrict__ shift, int n) {
  int i = threadIdx.x;
  if (i < n) {
    float inv = s[i] * rsqrtf(v[i] + 1e-5f);
    scale[i] = inv;
    shift[i] = (cb[i] - m[i]) * inv + b[i];
  }
}

// -------------------------- conv1a: fp32 direct, out grouped-NHWC f16 ------
__global__ __launch_bounds__(256) void conv1a_f16(
    const float* __restrict__ in, const float* __restrict__ wts,
    const float* __restrict__ cb, const float* __restrict__ s_,
    const float* __restrict__ b_, const float* __restrict__ m_,
    const float* __restrict__ v_, _Float16* __restrict__ out) {
  __shared__ __align__(16) float wl[5 * 8 * 20];
  __shared__ __align__(16) float il[12 * 68];
  int tid = threadIdx.x, bid = blockIdx.x;
  int img = bid / 30;
  int r = bid % 30;
  int cob = r / 15;
  int h0 = (r % 15) * 8;
  int cog = tid & 7, wg = (tid >> 3) & 3, hh = tid >> 5;
  float acc[4][16];
#pragma unroll
  for (int i = 0; i < 4; ++i)
#pragma unroll
    for (int j = 0; j < 16; ++j) acc[i][j] = 0.f;
  for (int idx = tid; idx < 32 * 25; idx += 256) {
    int rr = idx % 25, co = idx / 25;
    float v = wts[(cob * 32 + co) * 25 + rr];
    int kh = rr / 5, kw = rr % 5;
    wl[(kh * 8 + (co >> 2)) * 20 + (co & 3) * 5 + kw] = v;
  }
  for (int idx = tid; idx < 12 * 68; idx += 256) {
    int cc = idx % 68, rr = idx / 68;
    int hy = h0 + rr - 2, wx = cc - 2;
    float v = 0.f;
    if (hy >= 0 && hy < 120 && wx >= 0 && wx < 64)
      v = in[(size_t)img * 7680 + hy * 64 + wx];
    il[idx] = v;
  }
  __syncthreads();
#pragma unroll
  for (int kh = 0; kh < 5; ++kh) {
    const float* ir = &il[(hh + kh) * 68 + wg * 16];
    float iv[20];
#pragma unroll
    for (int i = 0; i < 5; ++i) {
      float4 p = *(const float4*)(ir + i * 4);
      iv[i * 4] = p.x; iv[i * 4 + 1] = p.y; iv[i * 4 + 2] = p.z; iv[i * 4 + 3] = p.w;
    }
    const float* wr = &wl[(kh * 8 + cog) * 20];
    float wv[20];
#pragma unroll
    for (int i = 0; i < 5; ++i) {
      float4 p = *(const float4*)(wr + i * 4);
      wv[i * 4] = p.x; wv[i * 4 + 1] = p.y; wv[i * 4 + 2] = p.z; wv[i * 4 + 3] = p.w;
    }
#pragma unroll
    for (int co = 0; co < 4; ++co)
#pragma unroll
      for (int kw = 0; kw < 5; ++kw) {
        float w1 = wv[co * 5 + kw];
#pragma unroll
        for (int w = 0; w < 16; ++w) acc[co][w] += w1 * iv[w + kw];
      }
  }
  int h = h0 + hh;
  int co0 = cob * 32 + cog * 4;
  float inv[4], bia[4];
#pragma unroll
  for (int i = 0; i < 4; ++i) {
    int c = co0 + i;
    inv[i] = s_[c] * rsqrtf(v_[c] + 1e-5f);
    bia[i] = (cb[c] - m_[c]) * inv[i] + b_[c];
  }
  int g = co0 >> 3, off = co0 & 7;
  _Float16* op = out + (((size_t)(img * 8 + g) * 120 + h) * 64) * 8 + off;
#pragma unroll
  for (int w = 0; w < 16; ++w) {
    half4 o;
#pragma unroll
    for (int i = 0; i < 4; ++i)
      o[i] = (_Float16)fmaxf(acc[i][w] * inv[i] + bia[i], 0.f);
    *(half4*)&op[(size_t)(wg * 16 + w) * 8] = o;
  }
}

// ------------------ MFMA implicit-GEMM 5x5 conv + BN + ReLU + maxpool2 -----
// 512 threads / 8 waves. Flat-pair K: 13 K=16 steps cover 25 taps + 1 pad.
// compute() software-pipelined (parity frag double-buffer + setprio) = r8.
// Output POOLED: grouped [img][CO/8][H/2][W/2][8] or (OUT_NCHW)
// [img][CO][H/2][W/2]. Requires W in {64,32,16}, ROWS even.
template <int CI, int CO, int H, int W, int BLK_M, bool OUT_NCHW, bool DBUF>
__global__ __launch_bounds__(512) void conv5_mfma(
    const _Float16* __restrict__ in, const _Float16* __restrict__ wt,
    const float* __restrict__ scale, const float* __restrict__ shift,
    _Float16* __restrict__ out) {
  constexpr int NW_M = BLK_M / 64;
  constexpr int NW_N = 8 / NW_M;
  constexpr int BLK_N = NW_N * 128;
  constexpr int ROWS = BLK_N / W;
  constexpr int TB = (H + ROWS - 1) / ROWS;
  constexpr int NCOB = CO / BLK_M;
  constexpr int HR = ROWS + 4;
  constexpr int HC = W + 4;
  constexpr int CIG = CI / 8;
  constexpr int OH = H / 2, OW = W / 2;
  constexpr int AITER = (HR * HC + 511) / 512;
  constexpr int WBYTES = 26 * BLK_M * 16;
  constexpr int WITER = (WBYTES + 8191) / 8192;
  constexpr int NBUF = DBUF ? 2 : 1;
  constexpr int ASZ = HR * HC * 8;
  constexpr int WSZ = 26 * BLK_M * 8;
  __shared__ __align__(16) _Float16 Alds[NBUF][ASZ];
  __shared__ __align__(16) _Float16 Wlds[NBUF][WSZ];

  int tid = threadIdx.x;
  int bid = blockIdx.x;
  int img = bid / (TB * NCOB);
  int r = bid % (TB * NCOB);
  int tb = r / NCOB;
  int cob = r % NCOB;
  int h0 = tb * ROWS;

  int wid = tid >> 6, l = tid & 63, lo = l & 31, hi = l >> 5;
  int widM = wid / NW_N, widN = wid % NW_N;

  int wbase[2];
#pragma unroll
  for (int mi = 0; mi < 2; ++mi)
    wbase[mi] = (hi * BLK_M + widM * 64 + mi * 32 + lo) * 8;
  int bbase[4];
#pragma unroll
  for (int j = 0; j < 4; ++j) {
    int pix = widN * 128 + j * 32 + lo;
    bbase[j] = ((pix / W) * HC + (pix % W)) * 8;
  }

  f32x16 acc[2][4];
#pragma unroll
  for (int mi = 0; mi < 2; ++mi)
#pragma unroll
    for (int j = 0; j < 4; ++j) acc[mi][j] = (f32x16){};

  auto loadA = [&](int cg, half8* areg) {
    const _Float16* ing = in + (size_t)(img * CIG + cg) * H * W * 8;
#pragma unroll
    for (int it = 0; it < AITER; ++it) {
      int i = tid + it * 512;
      half8 v = {};
      if (i < HR * HC) {
        int rr = i / HC, cc = i % HC;
        int hy = h0 + rr - 2, wx = cc - 2;
        if (hy >= 0 && hy < H && wx >= 0 && wx < W)
          v = *(const half8*)&ing[(size_t)(hy * W + wx) * 8];
      }
      areg[it] = v;
    }
  };
  auto issueW = [&](int cg, int buf) {
    const char* wsrc = (const char*)(wt + ((size_t)cg * 26 * CO + cob * BLK_M) * 8);
#pragma unroll
    for (int rr = 0; rr < WITER; ++rr) {
      int f = rr * 8192 + tid * 16;
      if (f < WBYTES) {
        int row = f / (BLK_M * 16);
        int off = f % (BLK_M * 16);
        async_copy16(wsrc + (size_t)row * (CO * 16) + off,
                     (char*)&Wlds[buf][0] + (rr * 8192 + wid * 1024));
      }
    }
  };
  auto writeA = [&](int buf, half8* areg) {
#pragma unroll
    for (int it = 0; it < AITER; ++it) {
      int i = tid + it * 512;
      if (i < HR * HC) *(half8*)&Alds[buf][i * 8] = areg[it];
    }
  };
  // fragment fetch for K-step p (pos = 2p + hi)
  auto ldfrag = [&](int buf, int p, half8 (&af)[2], half8 (&bf)[4]) {
    int pos0 = 2 * p, pos1 = 2 * p + 1;
    int off0 = (pos0 / 5) * HC + (pos0 % 5);
    int off1 = (pos1 < 25) ? (pos1 / 5) * HC + (pos1 % 5) : 0;
    int off = (hi ? off1 : off0) * 8;
#pragma unroll
    for (int mi = 0; mi < 2; ++mi)
      af[mi] = *(const half8*)&Wlds[buf][wbase[mi] + pos0 * BLK_M * 8];
#pragma unroll
    for (int j = 0; j < 4; ++j)
      bf[j] = *(const half8*)&Alds[buf][bbase[j] + off];
  };
  // software-pipelined: issue step p+1 reads before step p MFMAs.
  auto compute = [&](int buf) {
    half8 afA[2], bfA[4], afB[2], bfB[4];
    ldfrag(buf, 0, afA, bfA);
#pragma unroll
    for (int p = 0; p < 13; ++p) {
      const bool even = (p & 1) == 0;
      if (p + 1 < 13) {
        if (even) ldfrag(buf, p + 1, afB, bfB);
        else      ldfrag(buf, p + 1, afA, bfA);
      }
      __builtin_amdgcn_s_setprio(1);
#pragma unroll
      for (int mi = 0; mi < 2; ++mi)
#pragma unroll
        for (int j = 0; j < 4; ++j)
          acc[mi][j] = __builtin_amdgcn_mfma_f32_32x32x16_f16(
              even ? afA[mi] : afB[mi], even ? bfA[j] : bfB[j],
              acc[mi][j], 0, 0, 0);
      __builtin_amdgcn_s_setprio(0);
    }
  };

  if constexpr (DBUF) {
    half8 areg[AITER];
    loadA(0, areg);
    issueW(0, 0);
    writeA(0, areg);
    __syncthreads();
#pragma unroll 1
    for (int cg = 0; cg < CIG; ++cg) {
      int cur = cg & 1;
      if (cg + 1 < CIG) {
        loadA(cg + 1, areg);
        issueW(cg + 1, cur ^ 1);
      }
      compute(cur);
      if (cg + 1 < CIG) writeA(cur ^ 1, areg);
      __syncthreads();
    }
  } else {
#pragma unroll 1
    for (int cg = 0; cg < CIG; ++cg) {
      half8 areg[AITER];
      loadA(cg, areg);
      issueW(cg, 0);
      writeA(0, areg);
      __syncthreads();
      compute(0);
      __syncthreads();
    }
  }

  // ---- fused BN + ReLU + 2x2 maxpool epilogue ----
  if (!OUT_NCHW) {
    // W==64: rows widN*2+{0,1} = j pairs (0,2),(1,3); cols p*32+lo.
    // W==32: rows widN*4+j   = j pairs (0,1),(2,3); cols lo.
    constexpr int CGO = CO / 8;
    int gbase = (cob * BLK_M + widM * 64) >> 3;
    bool lane_ok = ((lo & 1) == 0);
#pragma unroll
    for (int mi = 0; mi < 2; ++mi) {
#pragma unroll
      for (int r4 = 0; r4 < 4; ++r4) {
        int g = gbase + mi * 4 + r4;
        int co0 = g * 8 + hi * 4;
        float4 sv = *(const float4*)&scale[co0];
        float4 tv = *(const float4*)&shift[co0];
        float sa[4] = {sv.x, sv.y, sv.z, sv.w};
        float ta[4] = {tv.x, tv.y, tv.z, tv.w};
#pragma unroll
        for (int p = 0; p < 2; ++p) {
          int ja = (W == 64) ? p : 2 * p;
          int jb = (W == 64) ? p + 2 : 2 * p + 1;
          int orow = (W == 64) ? (h0 >> 1) + widN : (h0 >> 1) + widN * 2 + p;
          int ocol = (W == 64) ? p * 16 + (lo >> 1) : (lo >> 1);
          half4 o;
#pragma unroll
          for (int c = 0; c < 4; ++c) {
            int reg = r4 * 4 + c;
            float v0 = fmaxf(acc[mi][ja][reg] * sa[c] + ta[c], 0.f);
            float v1 = fmaxf(acc[mi][jb][reg] * sa[c] + ta[c], 0.f);
            float m = fmaxf(v0, v1);
            m = fmaxf(m, __shfl_xor(m, 1, 64));
            o[c] = (_Float16)m;
          }
          if (lane_ok && orow < OH)
            *(half4*)&out[(((size_t)(img * CGO + g) * OH + orow) * OW + ocol) * 8 +
                          hi * 4] = o;
        }
      }
    }
  } else {
    // W==16: rows widN*8 + 2j + (lo>>4); row pair = lane^16, col pair = lane^1.
    bool lane_ok = ((lo & 1) == 0) && (lo < 16);
#pragma unroll
    for (int mi = 0; mi < 2; ++mi) {
#pragma unroll
      for (int reg = 0; reg < 16; ++reg) {
        int co = cob * BLK_M + widM * 64 + mi * 32 + (reg & 3) + 8 * (reg >> 2) + 4 * hi;
        float s = scale[co], t = shift[co];
#pragma unroll
        for (int j = 0; j < 4; ++j) {
          float v = fmaxf(acc[mi][j][reg] * s + t, 0.f);
          float m = fmaxf(v, __shfl_xor(v, 16, 64));
          m = fmaxf(m, __shfl_xor(m, 1, 64));
          int orow = (h0 >> 1) + widN * 4 + j;
          if (lane_ok && orow < OH)
            out[((size_t)(img * CO + co) * OH + orow) * OW + ((lo & 15) >> 1)] =
                (_Float16)m;
        }
      }
    }
  }
}

// --------------------------------------------------- fc1: f16 MFMA split-K -
// 120 K-splits x 2 N-tiles = 240 blocks, 4-5 chunks each. part[ks][n512][img128].
__global__ __launch_bounds__(256, 2) void fc1_mfma(const float* __restrict__ qv,
                                                   const _Float16* __restrict__ p3,
                                                   const float* __restrict__ w,
                                                   float* __restrict__ part) {
  __shared__ __align__(16) _Float16 Wl[8 * 256 * 8];  // [k8][n_loc][8]
  __shared__ __align__(16) _Float16 Bl[8 * 128 * 8];  // [k8][img][8]
  int tid = threadIdx.x;
  int ks = blockIdx.x >> 1, mt = blockIdx.x & 1;
  int wid = tid >> 6, l = tid & 63, lo = l & 31, hi = l >> 5;
  f32x16 acc[2][4];
#pragma unroll
  for (int mi = 0; mi < 2; ++mi)
#pragma unroll
    for (int j = 0; j < 4; ++j) acc[mi][j] = (f32x16){};

#pragma unroll 1
  for (int i3 = 0; i3 < 5; ++i3) {
    int c = ks + 120 * i3;
    if (c > 480) break;
    for (int idx = tid; idx < 2048; idx += 256) {
      int n_loc = idx >> 3, k8 = idx & 7;
      int n = mt * 256 + n_loc;
      half8 v = {};
      if (n < 500) {
        const float* src = w + (size_t)n * 30784 + c * 64 + k8 * 8;
        float4 f0 = *(const float4*)src;
        float4 f1 = *(const float4*)(src + 4);
        v[0] = (_Float16)f0.x; v[1] = (_Float16)f0.y;
        v[2] = (_Float16)f0.z; v[3] = (_Float16)f0.w;
        v[4] = (_Float16)f1.x; v[5] = (_Float16)f1.y;
        v[6] = (_Float16)f1.z; v[7] = (_Float16)f1.w;
      }
      *(half8*)&Wl[(size_t)(k8 * 256 + n_loc) * 8] = v;
    }
    for (int idx = tid; idx < 1024; idx += 256) {
      int img = idx >> 3, k8 = idx & 7;
      half8 v;
      if (c == 0) {
        const float* src = qv + img * 64 + k8 * 8;
        float4 f0 = *(const float4*)src;
        float4 f1 = *(const float4*)(src + 4);
        v[0] = (_Float16)f0.x; v[1] = (_Float16)f0.y;
        v[2] = (_Float16)f0.z; v[3] = (_Float16)f0.w;
        v[4] = (_Float16)f1.x; v[5] = (_Float16)f1.y;
        v[6] = (_Float16)f1.z; v[7] = (_Float16)f1.w;
      } else {
        v = *(const half8*)&p3[(size_t)img * 30720 + (c * 64 - 64) + k8 * 8];
      }
      *(half8*)&Bl[(size_t)(k8 * 128 + img) * 8] = v;
    }
    __syncthreads();
#pragma unroll
    for (int ks16 = 0; ks16 < 4; ++ks16) {
      half8 af[2], bf[4];
#pragma unroll
      for (int mi = 0; mi < 2; ++mi)
        af[mi] = *(const half8*)&Wl[(size_t)((ks16 * 2 + hi) * 256 + wid * 64 +
                                             mi * 32 + lo) * 8];
#pragma unroll
      for (int j = 0; j < 4; ++j)
        bf[j] = *(const half8*)&Bl[(size_t)((ks16 * 2 + hi) * 128 + j * 32 + lo) * 8];
#pragma unroll
      for (int mi = 0; mi < 2; ++mi)
#pragma unroll
        for (int j = 0; j < 4; ++j)
          acc[mi][j] = __builtin_amdgcn_mfma_f32_32x32x16_f16(
              af[mi], bf[j], acc[mi][j], 0, 0, 0);
    }
    __syncthreads();
  }
#pragma unroll
  for (int mi = 0; mi < 2; ++mi)
#pragma unroll
    for (int reg = 0; reg < 16; ++reg) {
      int n = mt * 256 + wid * 64 + mi * 32 + (reg & 3) + 8 * (reg >> 2) + 4 * hi;
#pragma unroll
      for (int j = 0; j < 4; ++j)
        part[((size_t)ks * 512 + n) * 128 + j * 32 + lo] = acc[mi][j][reg];
    }
}

__global__ __launch_bounds__(256) void fc1_reduce(const float* __restrict__ part,
                                                  const float* __restrict__ bias,
                                                  float* __restrict__ out) {
  int idx = blockIdx.x * 256 + threadIdx.x;  // 65536 = 512 n x 128 img
  int img = idx & 127, n = idx >> 7;
  float s = 0.f;
#pragma unroll 8
  for (int ks = 0; ks < 120; ++ks) s += part[((size_t)ks * 512 + n) * 128 + img];
  out[n * 128 + img] = (n < 500) ? fmaxf(s + bias[n], 0.f) : 0.f;
}

// -------------------------------------------------------- fc2 / fc3 --------
__global__ __launch_bounds__(256) void fc2_kernel(const float* __restrict__ qv,
                                                  const float* __restrict__ fc1o,
                                                  const float* __restrict__ w,
                                                  const float* __restrict__ bias,
                                                  float* __restrict__ out) {
  int idx = blockIdx.x * 256 + threadIdx.x;
  if (idx >= 128 * 500) return;
  int m = idx & 127, n = idx >> 7;
  const float* wr = w + (size_t)n * 564;
  float acc = 0.f;
#pragma unroll 8
  for (int k = 0; k < 64; ++k) acc += qv[m * 64 + k] * wr[k];
#pragma unroll 4
  for (int k = 0; k < 500; ++k) acc += fc1o[k * 128 + m] * wr[64 + k];
  out[n * 128 + m] = fmaxf(acc + bias[n], 0.f);
}

__global__ __launch_bounds__(256) void fc3_kernel(const float* __restrict__ qv,
                                                  const float* __restrict__ fc2o,
                                                  const float* __restrict__ w,
                                                  const float* __restrict__ bias,
                                                  float* __restrict__ out) {
  int tid = threadIdx.x;
  int m = tid >> 1, n = tid & 1;
  const float* wr = w + (size_t)n * 564;
  float acc = 0.f;
#pragma unroll 8
  for (int k = 0; k < 64; ++k) acc += qv[m * 64 + k] * wr[k];
#pragma unroll 4
  for (int k = 0; k < 500; ++k) acc += fc2o[k * 128 + m] * wr[64 + k];
  out[m * 2 + n] = acc + bias[n];
}

// ----------------------------------------------------------- launcher ------
extern "C" void kernel_launch(void* const* d_in, const int* in_sizes, int n_in,
                              void* d_out, int out_size, void* d_ws, size_t ws_size,
                              hipStream_t stream) {
  (void)in_sizes; (void)n_in; (void)out_size; (void)ws_size;
  const float* x      = (const float*)d_in[0];
  const float* qv     = (const float*)d_in[1];
  const float* basis  = (const float*)d_in[2];
  const float* c1aw   = (const float*)d_in[3];
  const float* c1ab   = (const float*)d_in[4];
  const float* c1bw   = (const float*)d_in[5];
  const float* c1bb   = (const float*)d_in[6];
  const float* c2aw   = (const float*)d_in[7];
  const float* c2ab   = (const float*)d_in[8];
  const float* c3aw   = (const float*)d_in[9];
  const float* c3ab   = (const float*)d_in[10];
  const float* bn1a_s = (const float*)d_in[11];
  const float* bn1a_b = (const float*)d_in[12];
  const float* bn1a_m = (const float*)d_in[13];
  const float* bn1a_v = (const float*)d_in[14];
  const float* bn1b_s = (const float*)d_in[15];
  const float* bn1b_b = (const float*)d_in[16];
  const float* bn1b_m = (const float*)d_in[17];
  const float* bn1b_v = (const float*)d_in[18];
  const float* bn2a_s = (const float*)d_in[19];
  const float* bn2a_b = (const float*)d_in[20];
  const float* bn2a_m = (const float*)d_in[21];
  const float* bn2a_v = (const float*)d_in[22];
  const float* bn3a_s = (const float*)d_in[23];
  const float* bn3a_b = (const float*)d_in[24];
  const float* bn3a_m = (const float*)d_in[25];
  const float* bn3a_v = (const float*)d_in[26];
  const float* fc1w   = (const float*)d_in[27];
  const float* fc1b   = (const float*)d_in[28];
  const float* fc2w   = (const float*)d_in[29];
  const float* fc2b   = (const float*)d_in[30];
  const float* fc3w   = (const float*)d_in[31];
  const float* fc3b   = (const float*)d_in[32];

  // ---- workspace (fl units), peak ~29.6M fl = 118 MB ----
  float* ws = (float*)d_ws;
  float* feat = ws;                                   //   983,040
  _Float16* wt1b = (_Float16*)(ws + 1000000);         //   106,496 h
  _Float16* wt2a = (_Float16*)(ws + 1070000);         //   212,992 h
  _Float16* wt3a = (_Float16*)(ws + 1200000);         //   851,968 h
  float* sc1b = ws + 1700000; float* sh1b = ws + 1700100;
  float* sc2a = ws + 1700200; float* sh2a = ws + 1700400;
  float* sc3a = ws + 1700600; float* sh3a = ws + 1701000;
  _Float16* p1 = (_Float16*)(ws + 1710000);           // 15,728,640 h (full)
  float* S = ws + 9600000;
  float* hpart   = S;                                 //  3,932,160 (dead early)
  _Float16* a1c  = (_Float16*)S;                      // 31,457,280 h (64-img chunk)
  _Float16* p2   = (_Float16*)(ws + 25400000);        //  7,864,320 h (full)
  _Float16* p3   = (_Float16*)(ws + 1710000);         //  3,932,160 h (p1 slot)
  float* f1p  = S;                                    //  7,864,320 fl (a1c dead)
  float* f1o  = ws + 29400000;                        //     65,536
  float* f2o  = ws + 29500000;                        //     65,536

  wtrans<64, 64><<<416, 256, 0, stream>>>(c1bw, wt1b);
  wtrans<64, 128><<<832, 256, 0, stream>>>(c2aw, wt2a);
  wtrans<128, 256><<<3328, 256, 0, stream>>>(c3aw, wt3a);
  bnprep<<<1, 256, 0, stream>>>(c1bb, bn1b_s, bn1b_b, bn1b_m, bn1b_v, sc1b, sh1b, 64);
  bnprep<<<1, 256, 0, stream>>>(c2ab, bn2a_s, bn2a_b, bn2a_m, bn2a_v, sc2a, sh2a, 128);
  bnprep<<<1, 256, 0, stream>>>(c3ab, bn3a_s, bn3a_b, bn3a_m, bn3a_v, sc3a, sh3a, 256);

  // ---- fused DCT + soft-histogram ----
  dcthist_kernel<<<512, 256, 0, stream>>>(x, basis, hpart);
  hist_reduce<<<3840, 256, 0, stream>>>(hpart, feat);

  // ---- conv1a + conv1b(MFMA, pooled out) : 2 chunks of 64 images ----
  for (int c = 0; c < 2; ++c) {
    const float* fin = feat + (size_t)c * 64 * 120 * 64;
    _Float16* pout = p1 + (size_t)c * 64 * 8 * 60 * 32 * 8;
    conv1a_f16<<<64 * 30, 256, 0, stream>>>(fin, c1aw, c1ab, bn1a_s, bn1a_b,
                                            bn1a_m, bn1a_v, a1c);
    conv5_mfma<64, 64, 120, 64, 64, false, false><<<64 * 8, 512, 0, stream>>>(
        a1c, wt1b, sc1b, sh1b, pout);
  }

  // ---- conv2a (full batch, pooled out) ----
  conv5_mfma<64, 128, 60, 32, 128, false, false><<<128 * 4, 512, 0, stream>>>(
      p1, wt2a, sc2a, sh2a, p2);

  // ---- conv3a (full batch, pooled NCHW out) ----
  conv5_mfma<128, 256, 30, 16, 128, true, false><<<128 * 2, 512, 0, stream>>>(
      p2, wt3a, sc3a, sh3a, p3);

  // ---- FC stack ----
  fc1_mfma<<<240, 256, 0, stream>>>(qv, p3, fc1w, f1p);
  fc1_reduce<<<256, 256, 0, stream>>>(f1p, fc1b, f1o);
  fc2_kernel<<<250, 256, 0, stream>>>(qv, f1o, fc2w, fc2b, f2o);
  fc3_kernel<<<1, 256, 0, stream>>>(qv, f2o, fc3w, fc3b, (float*)d_out);
}

// Round 8
// 762.380 us; speedup vs baseline: 1.0844x; 1.0082x over previous
//
#include <hip/hip_runtime.h>

// ============================================================================
// Djpegnet round 14 (= round 13 resubmitted; round-13 bench was an infra
// failure "container failed twice", no measurement obtained).
//  - dcthist: LDS histogram re-layout Hl[(ch*2+sub)*121 + k]. Old layout
//    (sub-major, stride 120) put the wave's 16 atomic targets on only 4
//    banks (120==24, 7680==0 mod 32) -> ~16-way serialization per atomic
//    round. New: 16 consecutive targets x odd stride 121 (25 mod 32,
//    coprime) -> 16 DISTINCT banks; residual cost = inherent 4-way
//    same-address sharing. ~Free change (readout re-indexed).
//  - bnprep x3 fused into one 512-thread launch (kills 2 launch latencies).
//  - Everything else identical to round 12 (best: 768.6us; conv5 structure
//    pinned at ~47% MfmaUtil after 5 null scheduling probes; L3-residency
//    noted: HBM-traffic optimizations are void for <126MB intermediates).
// ============================================================================

typedef _Float16 half8 __attribute__((ext_vector_type(8)));
typedef _Float16 half4 __attribute__((ext_vector_type(4)));
typedef float f32x16 __attribute__((ext_vector_type(16)));

__device__ __forceinline__ void async_copy16(const void* g, void* l) {
  __builtin_amdgcn_global_load_lds(
      (__attribute__((address_space(1))) void*)g,
      (__attribute__((address_space(3))) void*)l, 16, 0, 0);
}

// ------------------------------------------------- fused DCT + histogram ---
// 512 blocks (4 per image, 256 dct-blocks each), 256 threads.
// Each thread: one 8x8 block -> 64 coeffs in regs -> LDS channel histograms.
// Hl layout: [(ch*2+sub)][121] -- 16 concurrent targets on 16 distinct banks.
// hpart[gb][f(120)][c(64)] partial sums; reduced by hist_reduce.
__global__ __launch_bounds__(256) void dcthist_kernel(const float* __restrict__ x,
                                                      const float* __restrict__ basis,
                                                      float* __restrict__ hpart) {
  __shared__ __align__(16) float Bm[64];
  __shared__ float Hl[128 * 121];  // [(c*2+sub)][121]
  int tid = threadIdx.x;
  if (tid < 64) {
    int u = tid >> 3, xx = tid & 7;
    Bm[tid] = basis[(u * 8) * 64 + xx * 8] * 2.8284271247461903f;
  }
  for (int i = tid; i < 128 * 121; i += 256) Hl[i] = 0.f;
  __syncthreads();
  int gb = blockIdx.x;
  int b = gb >> 2;
  int blk = (gb & 3) * 256 + tid;
  int bi = blk >> 5, bj = blk & 31;
  const float* xp = x + (size_t)b * 65536 + (bi * 8) * 256 + bj * 8;
  float X[64];
#pragma unroll
  for (int r = 0; r < 8; ++r) {
    float4 p = *(const float4*)(xp + r * 256);
    float4 q = *(const float4*)(xp + r * 256 + 4);
    X[r * 8 + 0] = p.x; X[r * 8 + 1] = p.y; X[r * 8 + 2] = p.z; X[r * 8 + 3] = p.w;
    X[r * 8 + 4] = q.x; X[r * 8 + 5] = q.y; X[r * 8 + 6] = q.z; X[r * 8 + 7] = q.w;
  }
  float T[64];
#pragma unroll
  for (int u = 0; u < 8; ++u) {
    float t[8] = {0.f, 0.f, 0.f, 0.f, 0.f, 0.f, 0.f, 0.f};
#pragma unroll
    for (int xx = 0; xx < 8; ++xx) {
      float bm = Bm[u * 8 + xx];
#pragma unroll
      for (int y = 0; y < 8; ++y) t[y] += bm * X[xx * 8 + y];
    }
#pragma unroll
    for (int y = 0; y < 8; ++y) T[u * 8 + y] = t[y];
  }
  // histogram: v rotated per-thread (8 channels) x 2 subs = 16 targets/wave,
  // now mapped to 16 consecutive (ch*2+sub) slots * stride 121 -> 16 banks.
  int vr = tid & 7;
  int sub = (tid >> 3) & 1;
#pragma unroll 1
  for (int vv = 0; vv < 8; ++vv) {
    int v = (vv + vr) & 7;
    float dc[8] = {0.f, 0.f, 0.f, 0.f, 0.f, 0.f, 0.f, 0.f};
#pragma unroll
    for (int y = 0; y < 8; ++y) {
      float bm = Bm[v * 8 + y];
#pragma unroll
      for (int u = 0; u < 8; ++u) dc[u] += bm * T[u * 8 + y];
    }
#pragma unroll
    for (int u = 0; u < 8; ++u) {
      float d = dc[u];
      float* hc = Hl + ((u * 8 + v) * 2 + sub) * 121;
      float fl = floorf(d);
      float t0 = d - fl;
      int k = (int)fl + 60;
      if (t0 >= 2e-5f && t0 <= 1.f - 1.2e-4f) {
        if (k >= 0 && k < 120) atomicAdd(hc + k, 1.0f);
      } else {
        float s0 = 1.f / (1.f + expf(-1e6f * t0));
        float s1 = 1.f / (1.f + expf(1e6f * (1.f - t0)));
        if (k >= 1 && k <= 120) atomicAdd(hc + k - 1, 1.f - s0);
        if (k >= 0 && k < 120)  atomicAdd(hc + k, s0 - s1);
        if (k >= -1 && k < 119) atomicAdd(hc + k + 1, s1);
      }
    }
  }
  __syncthreads();
  for (int i = tid; i < 7680; i += 256) {
    int f = i >> 6, c = i & 63;
    hpart[(size_t)gb * 7680 + i] = Hl[(c * 2) * 121 + f] + Hl[(c * 2 + 1) * 121 + f];
  }
}

__global__ __launch_bounds__(256) void hist_reduce(const float* __restrict__ hpart,
                                                   float* __restrict__ feat) {
  int idx = blockIdx.x * 256 + threadIdx.x;  // 983040 = 128 img x 7680
  int b = idx / 7680, r = idx - b * 7680;
  float s = 0.f;
#pragma unroll
  for (int q = 0; q < 4; ++q) s += hpart[(size_t)(b * 4 + q) * 7680 + r];
  feat[(size_t)b * 7680 + r] = s * (1.f / 1024.f);
}

// ---------------------------------------- weight transpose + BN folding ----
// wt layout: [cg][k26][co][8ci], cg = ci/8, k26 = kh*5+kw (k==25 zeroed).
template <int CI, int CO>
__global__ __launch_bounds__(256) void wtrans(const float* __restrict__ w,
                                              _Float16* __restrict__ wt) {
  int i = blockIdx.x * 256 + threadIdx.x;
  if (i >= (CI / 8) * 26 * CO * 8) return;
  int c8 = i & 7;
  int t = i >> 3;
  int co = t % CO; t /= CO;
  int k = t % 26;
  int cg = t / 26;
  int ci = cg * 8 + c8;
  float v = (k < 25) ? w[((size_t)co * CI + ci) * 25 + k] : 0.f;
  wt[i] = (_Float16)v;
}

// fused BN-prep for all three conv5 BN stages (1 launch instead of 3).
__global__ __launch_bounds__(512) void bnprep3(
    const float* __restrict__ cb1, const float* __restrict__ s1,
    const float* __restrict__ b1, const float* __restrict__ m1,
    const float* __restrict__ v1, float* __restrict__ sc1, float* __restrict__ sh1,
    const float* __restrict__ cb2, const float* __restrict__ s2,
    const float* __restrict__ b2, const float* __restrict__ m2,
    const float* __restrict__ v2, float* __restrict__ sc2, float* __restrict__ sh2,
    const float* __restrict__ cb3, const float* __restrict__ s3,
    const float* __restrict__ b3, const float* __restrict__ m3,
    const float* __restrict__ v3, float* __restrict__ sc3, float* __restrict__ sh3) {
  int i = threadIdx.x;
  if (i < 64) {
    float inv = s1[i] * rsqrtf(v1[i] + 1e-5f);
    sc1[i] = inv;
    sh1[i] = (cb1[i] - m1[i]) * inv + b1[i];
  } else if (i < 192) {
    int j = i - 64;
    float inv = s2[j] * rsqrtf(v2[j] + 1e-5f);
    sc2[j] = inv;
    sh2[j] = (cb2[j] - m2[j]) * inv + b2[j];
  } else if (i < 448) {
    int j = i - 192;
    float inv = s3[j] * rsqrtf(v3[j] + 1e-5f);
    sc3[j] = inv;
    sh3[j] = (cb3[j] - m3[j]) * inv + b3[j];
  }
}

// -------------------------- conv1a: fp32 direct, out grouped-NHWC f16 ------
__global__ __launch_bounds__(256) void conv1a_f16(
    const float* __restrict__ in, const float* __restrict__ wts,
    const float* __restrict__ cb, const float* __restrict__ s_,
    const float* __restrict__ b_, const float* __restrict__ m_,
    const float* __restrict__ v_, _Float16* __restrict__ out) {
  __shared__ __align__(16) float wl[5 * 8 * 20];
  __shared__ __align__(16) float il[12 * 68];
  int tid = threadIdx.x, bid = blockIdx.x;
  int img = bid / 30;
  int r = bid % 30;
  int cob = r / 15;
  int h0 = (r % 15) * 8;
  int cog = tid & 7, wg = (tid >> 3) & 3, hh = tid >> 5;
  float acc[4][16];
#pragma unroll
  for (int i = 0; i < 4; ++i)
#pragma unroll
    for (int j = 0; j < 16; ++j) acc[i][j] = 0.f;
  for (int idx = tid; idx < 32 * 25; idx += 256) {
    int rr = idx % 25, co = idx / 25;
    float v = wts[(cob * 32 + co) * 25 + rr];
    int kh = rr / 5, kw = rr % 5;
    wl[(kh * 8 + (co >> 2)) * 20 + (co & 3) * 5 + kw] = v;
  }
  for (int idx = tid; idx < 12 * 68; idx += 256) {
    int cc = idx % 68, rr = idx / 68;
    int hy = h0 + rr - 2, wx = cc - 2;
    float v = 0.f;
    if (hy >= 0 && hy < 120 && wx >= 0 && wx < 64)
      v = in[(size_t)img * 7680 + hy * 64 + wx];
    il[idx] = v;
  }
  __syncthreads();
#pragma unroll
  for (int kh = 0; kh < 5; ++kh) {
    const float* ir = &il[(hh + kh) * 68 + wg * 16];
    float iv[20];
#pragma unroll
    for (int i = 0; i < 5; ++i) {
      float4 p = *(const float4*)(ir + i * 4);
      iv[i * 4] = p.x; iv[i * 4 + 1] = p.y; iv[i * 4 + 2] = p.z; iv[i * 4 + 3] = p.w;
    }
    const float* wr = &wl[(kh * 8 + cog) * 20];
    float wv[20];
#pragma unroll
    for (int i = 0; i < 5; ++i) {
      float4 p = *(const float4*)(wr + i * 4);
      wv[i * 4] = p.x; wv[i * 4 + 1] = p.y; wv[i * 4 + 2] = p.z; wv[i * 4 + 3] = p.w;
    }
#pragma unroll
    for (int co = 0; co < 4; ++co)
#pragma unroll
      for (int kw = 0; kw < 5; ++kw) {
        float w1 = wv[co * 5 + kw];
#pragma unroll
        for (int w = 0; w < 16; ++w) acc[co][w] += w1 * iv[w + kw];
      }
  }
  int h = h0 + hh;
  int co0 = cob * 32 + cog * 4;
  float inv[4], bia[4];
#pragma unroll
  for (int i = 0; i < 4; ++i) {
    int c = co0 + i;
    inv[i] = s_[c] * rsqrtf(v_[c] + 1e-5f);
    bia[i] = (cb[c] - m_[c]) * inv[i] + b_[c];
  }
  int g = co0 >> 3, off = co0 & 7;
  _Float16* op = out + (((size_t)(img * 8 + g) * 120 + h) * 64) * 8 + off;
#pragma unroll
  for (int w = 0; w < 16; ++w) {
    half4 o;
#pragma unroll
    for (int i = 0; i < 4; ++i)
      o[i] = (_Float16)fmaxf(acc[i][w] * inv[i] + bia[i], 0.f);
    *(half4*)&op[(size_t)(wg * 16 + w) * 8] = o;
  }
}

// ------------------ MFMA implicit-GEMM 5x5 conv + BN + ReLU + maxpool2 -----
// 512 threads / 8 waves. Flat-pair K: 13 K=16 steps cover 25 taps + 1 pad.
// compute() software-pipelined (parity frag double-buffer + setprio) = r8.
// Output POOLED: grouped [img][CO/8][H/2][W/2][8] or (OUT_NCHW)
// [img][CO][H/2][W/2]. Requires W in {64,32,16}, ROWS even.
template <int CI, int CO, int H, int W, int BLK_M, bool OUT_NCHW, bool DBUF>
__global__ __launch_bounds__(512) void conv5_mfma(
    const _Float16* __restrict__ in, const _Float16* __restrict__ wt,
    const float* __restrict__ scale, const float* __restrict__ shift,
    _Float16* __restrict__ out) {
  constexpr int NW_M = BLK_M / 64;
  constexpr int NW_N = 8 / NW_M;
  constexpr int BLK_N = NW_N * 128;
  constexpr int ROWS = BLK_N / W;
  constexpr int TB = (H + ROWS - 1) / ROWS;
  constexpr int NCOB = CO / BLK_M;
  constexpr int HR = ROWS + 4;
  constexpr int HC = W + 4;
  constexpr int CIG = CI / 8;
  constexpr int OH = H / 2, OW = W / 2;
  constexpr int AITER = (HR * HC + 511) / 512;
  constexpr int WBYTES = 26 * BLK_M * 16;
  constexpr int WITER = (WBYTES + 8191) / 8192;
  constexpr int NBUF = DBUF ? 2 : 1;
  constexpr int ASZ = HR * HC * 8;
  constexpr int WSZ = 26 * BLK_M * 8;
  __shared__ __align__(16) _Float16 Alds[NBUF][ASZ];
  __shared__ __align__(16) _Float16 Wlds[NBUF][WSZ];

  int tid = threadIdx.x;
  int bid = blockIdx.x;
  int img = bid / (TB * NCOB);
  int r = bid % (TB * NCOB);
  int tb = r / NCOB;
  int cob = r % NCOB;
  int h0 = tb * ROWS;

  int wid = tid >> 6, l = tid & 63, lo = l & 31, hi = l >> 5;
  int widM = wid / NW_N, widN = wid % NW_N;

  int wbase[2];
#pragma unroll
  for (int mi = 0; mi < 2; ++mi)
    wbase[mi] = (hi * BLK_M + widM * 64 + mi * 32 + lo) * 8;
  int bbase[4];
#pragma unroll
  for (int j = 0; j < 4; ++j) {
    int pix = widN * 128 + j * 32 + lo;
    bbase[j] = ((pix / W) * HC + (pix % W)) * 8;
  }

  f32x16 acc[2][4];
#pragma unroll
  for (int mi = 0; mi < 2; ++mi)
#pragma unroll
    for (int j = 0; j < 4; ++j) acc[mi][j] = (f32x16){};

  auto loadA = [&](int cg, half8* areg) {
    const _Float16* ing = in + (size_t)(img * CIG + cg) * H * W * 8;
#pragma unroll
    for (int it = 0; it < AITER; ++it) {
      int i = tid + it * 512;
      half8 v = {};
      if (i < HR * HC) {
        int rr = i / HC, cc = i % HC;
        int hy = h0 + rr - 2, wx = cc - 2;
        if (hy >= 0 && hy < H && wx >= 0 && wx < W)
          v = *(const half8*)&ing[(size_t)(hy * W + wx) * 8];
      }
      areg[it] = v;
    }
  };
  auto issueW = [&](int cg, int buf) {
    const char* wsrc = (const char*)(wt + ((size_t)cg * 26 * CO + cob * BLK_M) * 8);
#pragma unroll
    for (int rr = 0; rr < WITER; ++rr) {
      int f = rr * 8192 + tid * 16;
      if (f < WBYTES) {
        int row = f / (BLK_M * 16);
        int off = f % (BLK_M * 16);
        async_copy16(wsrc + (size_t)row * (CO * 16) + off,
                     (char*)&Wlds[buf][0] + (rr * 8192 + wid * 1024));
      }
    }
  };
  auto writeA = [&](int buf, half8* areg) {
#pragma unroll
    for (int it = 0; it < AITER; ++it) {
      int i = tid + it * 512;
      if (i < HR * HC) *(half8*)&Alds[buf][i * 8] = areg[it];
    }
  };
  // fragment fetch for K-step p (pos = 2p + hi)
  auto ldfrag = [&](int buf, int p, half8 (&af)[2], half8 (&bf)[4]) {
    int pos0 = 2 * p, pos1 = 2 * p + 1;
    int off0 = (pos0 / 5) * HC + (pos0 % 5);
    int off1 = (pos1 < 25) ? (pos1 / 5) * HC + (pos1 % 5) : 0;
    int off = (hi ? off1 : off0) * 8;
#pragma unroll
    for (int mi = 0; mi < 2; ++mi)
      af[mi] = *(const half8*)&Wlds[buf][wbase[mi] + pos0 * BLK_M * 8];
#pragma unroll
    for (int j = 0; j < 4; ++j)
      bf[j] = *(const half8*)&Alds[buf][bbase[j] + off];
  };
  // software-pipelined: issue step p+1 reads before step p MFMAs.
  auto compute = [&](int buf) {
    half8 afA[2], bfA[4], afB[2], bfB[4];
    ldfrag(buf, 0, afA, bfA);
#pragma unroll
    for (int p = 0; p < 13; ++p) {
      const bool even = (p & 1) == 0;
      if (p + 1 < 13) {
        if (even) ldfrag(buf, p + 1, afB, bfB);
        else      ldfrag(buf, p + 1, afA, bfA);
      }
      __builtin_amdgcn_s_setprio(1);
#pragma unroll
      for (int mi = 0; mi < 2; ++mi)
#pragma unroll
        for (int j = 0; j < 4; ++j)
          acc[mi][j] = __builtin_amdgcn_mfma_f32_32x32x16_f16(
              even ? afA[mi] : afB[mi], even ? bfA[j] : bfB[j],
              acc[mi][j], 0, 0, 0);
      __builtin_amdgcn_s_setprio(0);
    }
  };

  if constexpr (DBUF) {
    half8 areg[AITER];
    loadA(0, areg);
    issueW(0, 0);
    writeA(0, areg);
    __syncthreads();
#pragma unroll 1
    for (int cg = 0; cg < CIG; ++cg) {
      int cur = cg & 1;
      if (cg + 1 < CIG) {
        loadA(cg + 1, areg);
        issueW(cg + 1, cur ^ 1);
      }
      compute(cur);
      if (cg + 1 < CIG) writeA(cur ^ 1, areg);
      __syncthreads();
    }
  } else {
#pragma unroll 1
    for (int cg = 0; cg < CIG; ++cg) {
      half8 areg[AITER];
      loadA(cg, areg);
      issueW(cg, 0);
      writeA(0, areg);
      __syncthreads();
      compute(0);
      __syncthreads();
    }
  }

  // ---- fused BN + ReLU + 2x2 maxpool epilogue ----
  if (!OUT_NCHW) {
    // W==64: rows widN*2+{0,1} = j pairs (0,2),(1,3); cols p*32+lo.
    // W==32: rows widN*4+j   = j pairs (0,1),(2,3); cols lo.
    constexpr int CGO = CO / 8;
    int gbase = (cob * BLK_M + widM * 64) >> 3;
    bool lane_ok = ((lo & 1) == 0);
#pragma unroll
    for (int mi = 0; mi < 2; ++mi) {
#pragma unroll
      for (int r4 = 0; r4 < 4; ++r4) {
        int g = gbase + mi * 4 + r4;
        int co0 = g * 8 + hi * 4;
        float4 sv = *(const float4*)&scale[co0];
        float4 tv = *(const float4*)&shift[co0];
        float sa[4] = {sv.x, sv.y, sv.z, sv.w};
        float ta[4] = {tv.x, tv.y, tv.z, tv.w};
#pragma unroll
        for (int p = 0; p < 2; ++p) {
          int ja = (W == 64) ? p : 2 * p;
          int jb = (W == 64) ? p + 2 : 2 * p + 1;
          int orow = (W == 64) ? (h0 >> 1) + widN : (h0 >> 1) + widN * 2 + p;
          int ocol = (W == 64) ? p * 16 + (lo >> 1) : (lo >> 1);
          half4 o;
#pragma unroll
          for (int c = 0; c < 4; ++c) {
            int reg = r4 * 4 + c;
            float v0 = fmaxf(acc[mi][ja][reg] * sa[c] + ta[c], 0.f);
            float v1 = fmaxf(acc[mi][jb][reg] * sa[c] + ta[c], 0.f);
            float m = fmaxf(v0, v1);
            m = fmaxf(m, __shfl_xor(m, 1, 64));
            o[c] = (_Float16)m;
          }
          if (lane_ok && orow < OH)
            *(half4*)&out[(((size_t)(img * CGO + g) * OH + orow) * OW + ocol) * 8 +
                          hi * 4] = o;
        }
      }
    }
  } else {
    // W==16: rows widN*8 + 2j + (lo>>4); row pair = lane^16, col pair = lane^1.
    bool lane_ok = ((lo & 1) == 0) && (lo < 16);
#pragma unroll
    for (int mi = 0; mi < 2; ++mi) {
#pragma unroll
      for (int reg = 0; reg < 16; ++reg) {
        int co = cob * BLK_M + widM * 64 + mi * 32 + (reg & 3) + 8 * (reg >> 2) + 4 * hi;
        float s = scale[co], t = shift[co];
#pragma unroll
        for (int j = 0; j < 4; ++j) {
          float v = fmaxf(acc[mi][j][reg] * s + t, 0.f);
          float m = fmaxf(v, __shfl_xor(v, 16, 64));
          m = fmaxf(m, __shfl_xor(m, 1, 64));
          int orow = (h0 >> 1) + widN * 4 + j;
          if (lane_ok && orow < OH)
            out[((size_t)(img * CO + co) * OH + orow) * OW + ((lo & 15) >> 1)] =
                (_Float16)m;
        }
      }
    }
  }
}

// --------------------------------------------------- fc1: f16 MFMA split-K -
// 120 K-splits x 2 N-tiles = 240 blocks, 4-5 chunks each. part[ks][n512][img128].
__global__ __launch_bounds__(256, 2) void fc1_mfma(const float* __restrict__ qv,
                                                   const _Float16* __restrict__ p3,
                                                   const float* __restrict__ w,
                                                   float* __restrict__ part) {
  __shared__ __align__(16) _Float16 Wl[8 * 256 * 8];  // [k8][n_loc][8]
  __shared__ __align__(16) _Float16 Bl[8 * 128 * 8];  // [k8][img][8]
  int tid = threadIdx.x;
  int ks = blockIdx.x >> 1, mt = blockIdx.x & 1;
  int wid = tid >> 6, l = tid & 63, lo = l & 31, hi = l >> 5;
  f32x16 acc[2][4];
#pragma unroll
  for (int mi = 0; mi < 2; ++mi)
#pragma unroll
    for (int j = 0; j < 4; ++j) acc[mi][j] = (f32x16){};

#pragma unroll 1
  for (int i3 = 0; i3 < 5; ++i3) {
    int c = ks + 120 * i3;
    if (c > 480) break;
    for (int idx = tid; idx < 2048; idx += 256) {
      int n_loc = idx >> 3, k8 = idx & 7;
      int n = mt * 256 + n_loc;
      half8 v = {};
      if (n < 500) {
        const float* src = w + (size_t)n * 30784 + c * 64 + k8 * 8;
        float4 f0 = *(const float4*)src;
        float4 f1 = *(const float4*)(src + 4);
        v[0] = (_Float16)f0.x; v[1] = (_Float16)f0.y;
        v[2] = (_Float16)f0.z; v[3] = (_Float16)f0.w;
        v[4] = (_Float16)f1.x; v[5] = (_Float16)f1.y;
        v[6] = (_Float16)f1.z; v[7] = (_Float16)f1.w;
      }
      *(half8*)&Wl[(size_t)(k8 * 256 + n_loc) * 8] = v;
    }
    for (int idx = tid; idx < 1024; idx += 256) {
      int img = idx >> 3, k8 = idx & 7;
      half8 v;
      if (c == 0) {
        const float* src = qv + img * 64 + k8 * 8;
        float4 f0 = *(const float4*)src;
        float4 f1 = *(const float4*)(src + 4);
        v[0] = (_Float16)f0.x; v[1] = (_Float16)f0.y;
        v[2] = (_Float16)f0.z; v[3] = (_Float16)f0.w;
        v[4] = (_Float16)f1.x; v[5] = (_Float16)f1.y;
        v[6] = (_Float16)f1.z; v[7] = (_Float16)f1.w;
      } else {
        v = *(const half8*)&p3[(size_t)img * 30720 + (c * 64 - 64) + k8 * 8];
      }
      *(half8*)&Bl[(size_t)(k8 * 128 + img) * 8] = v;
    }
    __syncthreads();
#pragma unroll
    for (int ks16 = 0; ks16 < 4; ++ks16) {
      half8 af[2], bf[4];
#pragma unroll
      for (int mi = 0; mi < 2; ++mi)
        af[mi] = *(const half8*)&Wl[(size_t)((ks16 * 2 + hi) * 256 + wid * 64 +
                                             mi * 32 + lo) * 8];
#pragma unroll
      for (int j = 0; j < 4; ++j)
        bf[j] = *(const half8*)&Bl[(size_t)((ks16 * 2 + hi) * 128 + j * 32 + lo) * 8];
#pragma unroll
      for (int mi = 0; mi < 2; ++mi)
#pragma unroll
        for (int j = 0; j < 4; ++j)
          acc[mi][j] = __builtin_amdgcn_mfma_f32_32x32x16_f16(
              af[mi], bf[j], acc[mi][j], 0, 0, 0);
    }
    __syncthreads();
  }
#pragma unroll
  for (int mi = 0; mi < 2; ++mi)
#pragma unroll
    for (int reg = 0; reg < 16; ++reg) {
      int n = mt * 256 + wid * 64 + mi * 32 + (reg & 3) + 8 * (reg >> 2) + 4 * hi;
#pragma unroll
      for (int j = 0; j < 4; ++j)
        part[((size_t)ks * 512 + n) * 128 + j * 32 + lo] = acc[mi][j][reg];
    }
}

__global__ __launch_bounds__(256) void fc1_reduce(const float* __restrict__ part,
                                                  const float* __restrict__ bias,
                                                  float* __restrict__ out) {
  int idx = blockIdx.x * 256 + threadIdx.x;  // 65536 = 512 n x 128 img
  int img = idx & 127, n = idx >> 7;
  float s = 0.f;
#pragma unroll 8
  for (int ks = 0; ks < 120; ++ks) s += part[((size_t)ks * 512 + n) * 128 + img];
  out[n * 128 + img] = (n < 500) ? fmaxf(s + bias[n], 0.f) : 0.f;
}

// -------------------------------------------------------- fc2 / fc3 --------
__global__ __launch_bounds__(256) void fc2_kernel(const float* __restrict__ qv,
                                                  const float* __restrict__ fc1o,
                                                  const float* __restrict__ w,
                                                  const float* __restrict__ bias,
                                                  float* __restrict__ out) {
  int idx = blockIdx.x * 256 + threadIdx.x;
  if (idx >= 128 * 500) return;
  int m = idx & 127, n = idx >> 7;
  const float* wr = w + (size_t)n * 564;
  float acc = 0.f;
#pragma unroll 8
  for (int k = 0; k < 64; ++k) acc += qv[m * 64 + k] * wr[k];
#pragma unroll 4
  for (int k = 0; k < 500; ++k) acc += fc1o[k * 128 + m] * wr[64 + k];
  out[n * 128 + m] = fmaxf(acc + bias[n], 0.f);
}

__global__ __launch_bounds__(256) void fc3_kernel(const float* __restrict__ qv,
                                                  const float* __restrict__ fc2o,
                                                  const float* __restrict__ w,
                                                  const float* __restrict__ bias,
                                                  float* __restrict__ out) {
  int tid = threadIdx.x;
  int m = tid >> 1, n = tid & 1;
  const float* wr = w + (size_t)n * 564;
  float acc = 0.f;
#pragma unroll 8
  for (int k = 0; k < 64; ++k) acc += qv[m * 64 + k] * wr[k];
#pragma unroll 4
  for (int k = 0; k < 500; ++k) acc += fc2o[k * 128 + m] * wr[64 + k];
  out[m * 2 + n] = acc + bias[n];
}

// ----------------------------------------------------------- launcher ------
extern "C" void kernel_launch(void* const* d_in, const int* in_sizes, int n_in,
                              void* d_out, int out_size, void* d_ws, size_t ws_size,
                              hipStream_t stream) {
  (void)in_sizes; (void)n_in; (void)out_size; (void)ws_size;
  const float* x      = (const float*)d_in[0];
  const float* qv     = (const float*)d_in[1];
  const float* basis  = (const float*)d_in[2];
  const float* c1aw   = (const float*)d_in[3];
  const float* c1ab   = (const float*)d_in[4];
  const float* c1bw   = (const float*)d_in[5];
  const float* c1bb   = (const float*)d_in[6];
  const float* c2aw   = (const float*)d_in[7];
  const float* c2ab   = (const float*)d_in[8];
  const float* c3aw   = (const float*)d_in[9];
  const float* c3ab   = (const float*)d_in[10];
  const float* bn1a_s = (const float*)d_in[11];
  const float* bn1a_b = (const float*)d_in[12];
  const float* bn1a_m = (const float*)d_in[13];
  const float* bn1a_v = (const float*)d_in[14];
  const float* bn1b_s = (const float*)d_in[15];
  const float* bn1b_b = (const float*)d_in[16];
  const float* bn1b_m = (const float*)d_in[17];
  const float* bn1b_v = (const float*)d_in[18];
  const float* bn2a_s = (const float*)d_in[19];
  const float* bn2a_b = (const float*)d_in[20];
  const float* bn2a_m = (const float*)d_in[21];
  const float* bn2a_v = (const float*)d_in[22];
  const float* bn3a_s = (const float*)d_in[23];
  const float* bn3a_b = (const float*)d_in[24];
  const float* bn3a_m = (const float*)d_in[25];
  const float* bn3a_v = (const float*)d_in[26];
  const float* fc1w   = (const float*)d_in[27];
  const float* fc1b   = (const float*)d_in[28];
  const float* fc2w   = (const float*)d_in[29];
  const float* fc2b   = (const float*)d_in[30];
  const float* fc3w   = (const float*)d_in[31];
  const float* fc3b   = (const float*)d_in[32];

  // ---- workspace (fl units), peak ~29.6M fl = 118 MB ----
  float* ws = (float*)d_ws;
  float* feat = ws;                                   //   983,040
  _Float16* wt1b = (_Float16*)(ws + 1000000);         //   106,496 h
  _Float16* wt2a = (_Float16*)(ws + 1070000);         //   212,992 h
  _Float16* wt3a = (_Float16*)(ws + 1200000);         //   851,968 h
  float* sc1b = ws + 1700000; float* sh1b = ws + 1700100;
  float* sc2a = ws + 1700200; float* sh2a = ws + 1700400;
  float* sc3a = ws + 1700600; float* sh3a = ws + 1701000;
  _Float16* p1 = (_Float16*)(ws + 1710000);           // 15,728,640 h (full)
  float* S = ws + 9600000;
  float* hpart   = S;                                 //  3,932,160 (dead early)
  _Float16* a1c  = (_Float16*)S;                      // 31,457,280 h (64-img chunk)
  _Float16* p2   = (_Float16*)(ws + 25400000);        //  7,864,320 h (full)
  _Float16* p3   = (_Float16*)(ws + 1710000);         //  3,932,160 h (p1 slot)
  float* f1p  = S;                                    //  7,864,320 fl (a1c dead)
  float* f1o  = ws + 29400000;                        //     65,536
  float* f2o  = ws + 29500000;                        //     65,536

  wtrans<64, 64><<<416, 256, 0, stream>>>(c1bw, wt1b);
  wtrans<64, 128><<<832, 256, 0, stream>>>(c2aw, wt2a);
  wtrans<128, 256><<<3328, 256, 0, stream>>>(c3aw, wt3a);
  bnprep3<<<1, 512, 0, stream>>>(c1bb, bn1b_s, bn1b_b, bn1b_m, bn1b_v, sc1b, sh1b,
                                 c2ab, bn2a_s, bn2a_b, bn2a_m, bn2a_v, sc2a, sh2a,
                                 c3ab, bn3a_s, bn3a_b, bn3a_m, bn3a_v, sc3a, sh3a);

  // ---- fused DCT + soft-histogram ----
  dcthist_kernel<<<512, 256, 0, stream>>>(x, basis, hpart);
  hist_reduce<<<3840, 256, 0, stream>>>(hpart, feat);

  // ---- conv1a + conv1b(MFMA, pooled out) : 2 chunks of 64 images ----
  for (int c = 0; c < 2; ++c) {
    const float* fin = feat + (size_t)c * 64 * 120 * 64;
    _Float16* pout = p1 + (size_t)c * 64 * 8 * 60 * 32 * 8;
    conv1a_f16<<<64 * 30, 256, 0, stream>>>(fin, c1aw, c1ab, bn1a_s, bn1a_b,
                                            bn1a_m, bn1a_v, a1c);
    conv5_mfma<64, 64, 120, 64, 64, false, false><<<64 * 8, 512, 0, stream>>>(
        a1c, wt1b, sc1b, sh1b, pout);
  }

  // ---- conv2a (full batch, pooled out) ----
  conv5_mfma<64, 128, 60, 32, 128, false, false><<<128 * 4, 512, 0, stream>>>(
      p1, wt2a, sc2a, sh2a, p2);

  // ---- conv3a (full batch, pooled NCHW out) ----
  conv5_mfma<128, 256, 30, 16, 128, true, false><<<128 * 2, 512, 0, stream>>>(
      p2, wt3a, sc3a, sh3a, p3);

  // ---- FC stack ----
  fc1_mfma<<<240, 256, 0, stream>>>(qv, p3, fc1w, f1p);
  fc1_reduce<<<256, 256, 0, stream>>>(f1p, fc1b, f1o);
  fc2_kernel<<<250, 256, 0, stream>>>(qv, f1o, fc2w, fc2b, f2o);
  fc3_kernel<<<1, 256, 0, stream>>>(qv, f2o, fc3w, fc3b, (float*)d_out);
}